// Round 1
// baseline (307.266 us; speedup 1.0000x reference)
//
#include <hip/hip_runtime.h>

#define Bn 16
#define Sn 64
#define Cn 20
#define Tn 2048
#define TPB 256
#define KS 32
#define Kc (Tn / KS)    // 64
#define PITCH 68        // LDS row pitch in words: 16B-aligned, rows offset 4 banks -> <=2-way (free)

// One MLP layer for 2 time points: in[m][c] -> out[m][j], ReLU.
// Weights/biases read DIRECTLY from global with wave-uniform compile-time
// indices -> backend scalarizes to s_load, FMA uses SGPR operand.
// c-outer / j-inner so each weight row W[c*NJ .. c*NJ+NJ-1] is contiguous
// (merges into s_load_dwordx4/x8/x16).
template <int NI, int NJ>
__device__ __forceinline__ void layerS(const float (&in)[2][NI], float (&out)[2][NJ],
                                       const float* __restrict__ W,
                                       const float* __restrict__ bb)
{
    float acc[2][NJ];
    #pragma unroll
    for (int j = 0; j < NJ; ++j) {
        const float bj = bb[j];
        acc[0][j] = bj; acc[1][j] = bj;
    }
    #pragma unroll
    for (int c = 0; c < NI; ++c) {
        const float x0 = in[0][c], x1 = in[1][c];
        #pragma unroll
        for (int j = 0; j < NJ; ++j) {
            const float w = W[c * NJ + j];   // uniform address -> SGPR
            acc[0][j] = fmaf(x0, w, acc[0][j]);
            acc[1][j] = fmaf(x1, w, acc[1][j]);
        }
    }
    #pragma unroll
    for (int j = 0; j < NJ; ++j) {
        out[0][j] = fmaxf(acc[0][j], 0.f);
        out[1][j] = fmaxf(acc[1][j], 0.f);
    }
}

// ---------------- Kernel A: MLP. grid = B*S*4, no LDS weight staging ----------------
__global__ __launch_bounds__(256) void mlp_kernel(
    const float* __restrict__ data,
    const float* __restrict__ W1, const float* __restrict__ b1,
    const float* __restrict__ W2, const float* __restrict__ b2,
    const float* __restrict__ W3, const float* __restrict__ b3,
    const float* __restrict__ W4, const float* __restrict__ b4,
    const float* __restrict__ W5, const float* __restrict__ b5,
    float* __restrict__ y, double* __restrict__ Rp)
{
    __shared__ double rbuf[TPB / 64];

    const int tid = threadIdx.x;
    const int bs = blockIdx.x >> 2;
    const int qt = blockIdx.x & 3;
    const float* base = data + (size_t)bs * Cn * Tn;
    const int t0 = qt * (Tn / 4) + tid * 2;

    float x[2][20], h[2][20];
    #pragma unroll
    for (int c = 0; c < 20; ++c) {
        const float2 v = *(const float2*)&base[c * Tn + t0];
        x[0][c] = v.x; x[1][c] = v.y;
    }

    layerS<20, 20>(x, h, W1, b1);   // x -> h
    layerS<20, 20>(h, x, W2, b2);   // h -> x
    layerS<20, 20>(x, h, W3, b3);   // x -> h
    float g[2][10];
    layerS<20, 10>(h, g, W4, b4);   // h -> g
    float o[2][1];
    layerS<10, 1>(g, o, W5, b5);    // g -> o (final ReLU included)

    float2 st; st.x = o[0][0]; st.y = o[1][0];
    *(float2*)&y[(size_t)bs * Tn + t0] = st;

    // block row-sum for the mean: wave shuffle reduce, then 4-way LDS combine
    double r = (double)o[0][0] + (double)o[1][0];
    #pragma unroll
    for (int off = 32; off > 0; off >>= 1) r += __shfl_down(r, off, 64);
    if ((tid & 63) == 0) rbuf[tid >> 6] = r;
    __syncthreads();
    if (tid == 0) Rp[blockIdx.x] = rbuf[0] + rbuf[1] + rbuf[2] + rbuf[3];
}

// ---------------- Kernel B: Gram via K-split GEMM tile + fp32 atomics ----------------
// grid = Bn * KS (=512, 2 blocks/CU); block stages 64 rows x Kc centered fp32 in LDS,
// each thread computes a 4x4 tile of the 64x64 Gram partial, atomicAdds to covf.
__global__ __launch_bounds__(256) void cov_kernel(
    const float* __restrict__ y, const double* __restrict__ Rp,
    float* __restrict__ covf)
{
    __shared__ __align__(16) float S[64 * PITCH];   // ~17.4 KB
    __shared__ double smean[64];

    const int tid = threadIdx.x;
    const int b  = blockIdx.x >> 5;
    const int ks = blockIdx.x & 31;

    if (tid < 64) {
        const int q = ((b << 6) + tid) * 4;
        smean[tid] = (Rp[q] + Rp[q + 1] + Rp[q + 2] + Rp[q + 3]) * (1.0 / Tn);
    }
    __syncthreads();

    // stage: 64 rows x Kc floats, centered (fp64 mean), fp32 in LDS
    const float* ybase = y + (size_t)(b << 6) * Tn + ks * Kc;
    #pragma unroll
    for (int it = 0; it < (64 * Kc / 4) / TPB; ++it) {   // 4 iters
        const int f4 = tid + it * TPB;
        const int row = f4 >> 4;                          // Kc/4 = 16 float4 per row
        const int k4 = f4 & 15;
        const float4 v = *(const float4*)&ybase[(size_t)row * Tn + k4 * 4];
        const double m = smean[row];
        float4 c;
        c.x = (float)((double)v.x - m);
        c.y = (float)((double)v.y - m);
        c.z = (float)((double)v.z - m);
        c.w = (float)((double)v.w - m);
        *(float4*)&S[row * PITCH + k4 * 4] = c;
    }
    __syncthreads();

    // compute: thread (ty,tx) -> rows {ty+16a}, cols {tx+16j}
    const int ty = tid >> 4, tx = tid & 15;
    float acc[4][4];
    #pragma unroll
    for (int a = 0; a < 4; ++a)
        #pragma unroll
        for (int j = 0; j < 4; ++j) acc[a][j] = 0.f;

    for (int kq = 0; kq < Kc / 4; ++kq) {
        float4 av[4], bv[4];
        #pragma unroll
        for (int a = 0; a < 4; ++a) av[a] = *(const float4*)&S[(ty + 16 * a) * PITCH + kq * 4];
        #pragma unroll
        for (int j = 0; j < 4; ++j) bv[j] = *(const float4*)&S[(tx + 16 * j) * PITCH + kq * 4];
        #pragma unroll
        for (int a = 0; a < 4; ++a)
            #pragma unroll
            for (int j = 0; j < 4; ++j) {
                acc[a][j] = fmaf(av[a].x, bv[j].x, acc[a][j]);
                acc[a][j] = fmaf(av[a].y, bv[j].y, acc[a][j]);
                acc[a][j] = fmaf(av[a].z, bv[j].z, acc[a][j]);
                acc[a][j] = fmaf(av[a].w, bv[j].w, acc[a][j]);
            }
    }

    float* cb = covf + ((size_t)b << 12);
    #pragma unroll
    for (int a = 0; a < 4; ++a) {
        const int row = ty + 16 * a;
        #pragma unroll
        for (int j = 0; j < 4; ++j)
            atomicAdd(&cb[(row << 6) + tx + 16 * j], acc[a][j]);
    }
}

// ---------------- Kernel C: corr + output (fp64 ratio, NaN-propagating clip) ----------------
// Note: covf is the UNSCALED Gram (no 1/(T-1)) — the scale cancels in corr.
__global__ __launch_bounds__(256) void corr_kernel(
    const float* __restrict__ covf, float* __restrict__ out)
{
    const int i = blockIdx.x * TPB + threadIdx.x;
    if (i >= Bn * Sn * Sn) return;
    const int b = i / (Sn * Sn);
    const int rem = i % (Sn * Sn);
    const int s = rem / Sn, u = rem % Sn;
    const double css = (double)covf[((size_t)b * Sn + s) * Sn + s];
    const double cuu = (double)covf[((size_t)b * Sn + u) * Sn + u];
    const double csu = (double)covf[i];
    double r = csu / sqrt(css * cuu);
    r = (r < -1.0) ? -1.0 : ((r > 1.0) ? 1.0 : r);   // NaN-propagating clip
    out[i] = (float)(1.0 - r);
}

extern "C" void kernel_launch(void* const* d_in, const int* in_sizes, int n_in,
                              void* d_out, int out_size, void* d_ws, size_t ws_size,
                              hipStream_t stream) {
    const float* data = (const float*)d_in[0];
    const float* W1 = (const float*)d_in[1];  const float* b1 = (const float*)d_in[2];
    const float* W2 = (const float*)d_in[3];  const float* b2 = (const float*)d_in[4];
    const float* W3 = (const float*)d_in[5];  const float* b3 = (const float*)d_in[6];
    const float* W4 = (const float*)d_in[7];  const float* b4 = (const float*)d_in[8];
    const float* W5 = (const float*)d_in[9];  const float* b5 = (const float*)d_in[10];
    float* out = (float*)d_out;

    // ws layout: y fp32 (8 MB) | covf fp32 (256 KB) | Rp fp64 (32 KB)
    float* y = (float*)d_ws;
    float* covf = (float*)((char*)d_ws + (size_t)Bn * Sn * Tn * sizeof(float));
    double* Rp = (double*)((char*)covf + (size_t)Bn * Sn * Sn * sizeof(float));

    hipMemsetAsync(covf, 0, (size_t)Bn * Sn * Sn * sizeof(float), stream);
    mlp_kernel<<<Bn * Sn * 4, TPB, 0, stream>>>(data, W1, b1, W2, b2, W3, b3, W4, b4, W5, b5, y, Rp);
    cov_kernel<<<Bn * KS, TPB, 0, stream>>>(y, Rp, covf);
    corr_kernel<<<(Bn * Sn * Sn + TPB - 1) / TPB, TPB, 0, stream>>>(covf, out);
}

// Round 3
// 304.431 us; speedup vs baseline: 1.0093x; 1.0093x over previous
//
#include <hip/hip_runtime.h>

#define Bn 16
#define Sn 64
#define Cn 20
#define Tn 2048
#define TPB 256
#define KS 32
#define Kc (Tn / KS)    // 64
#define PITCH 68        // LDS row pitch in words: 16B-aligned, rows offset 4 banks -> <=2-way (free)

// One MLP layer for 2 time points: in[m][c] -> out[m][j], ReLU.
// Weights/biases read DIRECTLY from global with wave-uniform compile-time
// indices -> backend scalarizes to s_load, FMA uses SGPR operand.
// c-outer / j-inner so each weight row W[c*NJ .. c*NJ+NJ-1] is contiguous
// (merges into s_load_dwordx4/x8/x16).
template <int NI, int NJ>
__device__ __forceinline__ void layerS(const float (&in)[2][NI], float (&out)[2][NJ],
                                       const float* __restrict__ W,
                                       const float* __restrict__ bb)
{
    float acc[2][NJ];
    #pragma unroll
    for (int j = 0; j < NJ; ++j) {
        const float bj = bb[j];
        acc[0][j] = bj; acc[1][j] = bj;
    }
    #pragma unroll
    for (int c = 0; c < NI; ++c) {
        const float x0 = in[0][c], x1 = in[1][c];
        #pragma unroll
        for (int j = 0; j < NJ; ++j) {
            const float w = W[c * NJ + j];   // uniform address -> SGPR
            acc[0][j] = fmaf(x0, w, acc[0][j]);
            acc[1][j] = fmaf(x1, w, acc[1][j]);
        }
    }
    #pragma unroll
    for (int j = 0; j < NJ; ++j) {
        out[0][j] = fmaxf(acc[0][j], 0.f);
        out[1][j] = fmaxf(acc[1][j], 0.f);
    }
}

// ---------------- Kernel A: MLP. grid = B*S*4 ----------------
// __launch_bounds__(256, 4): min 4 waves/EU -> VGPR cap 128. The layer
// boundary needs in[2][20]+acc[2][20] ~= 80-90 live VGPRs; the default
// heuristic capped at 44 and SPILLED the activation arrays to scratch
// (R0/R1 both 113 us, insensitive to weight-path changes). 4 waves/SIMD
// with 20 independent FMA chains per sample is ample latency hiding.
__global__ __launch_bounds__(256, 4) void mlp_kernel(
    const float* __restrict__ data,
    const float* __restrict__ W1, const float* __restrict__ b1,
    const float* __restrict__ W2, const float* __restrict__ b2,
    const float* __restrict__ W3, const float* __restrict__ b3,
    const float* __restrict__ W4, const float* __restrict__ b4,
    const float* __restrict__ W5, const float* __restrict__ b5,
    float* __restrict__ y, double* __restrict__ Rp)
{
    __shared__ double rbuf[TPB / 64];

    const int tid = threadIdx.x;
    const int bs = blockIdx.x >> 2;
    const int qt = blockIdx.x & 3;
    const float* base = data + (size_t)bs * Cn * Tn;
    const int t0 = qt * (Tn / 4) + tid * 2;

    float x[2][20], h[2][20];
    #pragma unroll
    for (int c = 0; c < 20; ++c) {
        const float2 v = *(const float2*)&base[c * Tn + t0];
        x[0][c] = v.x; x[1][c] = v.y;
    }

    layerS<20, 20>(x, h, W1, b1);   // x -> h
    layerS<20, 20>(h, x, W2, b2);   // h -> x
    layerS<20, 20>(x, h, W3, b3);   // x -> h
    float g[2][10];
    layerS<20, 10>(h, g, W4, b4);   // h -> g
    float o[2][1];
    layerS<10, 1>(g, o, W5, b5);    // g -> o (final ReLU included)

    float2 st; st.x = o[0][0]; st.y = o[1][0];
    *(float2*)&y[(size_t)bs * Tn + t0] = st;

    // block row-sum for the mean: wave shuffle reduce, then 4-way LDS combine
    double r = (double)o[0][0] + (double)o[1][0];
    #pragma unroll
    for (int off = 32; off > 0; off >>= 1) r += __shfl_down(r, off, 64);
    if ((tid & 63) == 0) rbuf[tid >> 6] = r;
    __syncthreads();
    if (tid == 0) Rp[blockIdx.x] = rbuf[0] + rbuf[1] + rbuf[2] + rbuf[3];
}

// ---------------- Kernel B: Gram via K-split GEMM tile + fp32 atomics ----------------
// grid = Bn * KS (=512, 2 blocks/CU); block stages 64 rows x Kc centered fp32 in LDS,
// each thread computes a 4x4 tile of the 64x64 Gram partial, atomicAdds to covf.
__global__ __launch_bounds__(256) void cov_kernel(
    const float* __restrict__ y, const double* __restrict__ Rp,
    float* __restrict__ covf)
{
    __shared__ __align__(16) float S[64 * PITCH];   // ~17.4 KB
    __shared__ double smean[64];

    const int tid = threadIdx.x;
    const int b  = blockIdx.x >> 5;
    const int ks = blockIdx.x & 31;

    if (tid < 64) {
        const int q = ((b << 6) + tid) * 4;
        smean[tid] = (Rp[q] + Rp[q + 1] + Rp[q + 2] + Rp[q + 3]) * (1.0 / Tn);
    }
    __syncthreads();

    // stage: 64 rows x Kc floats, centered (fp64 mean), fp32 in LDS
    const float* ybase = y + (size_t)(b << 6) * Tn + ks * Kc;
    #pragma unroll
    for (int it = 0; it < (64 * Kc / 4) / TPB; ++it) {   // 4 iters
        const int f4 = tid + it * TPB;
        const int row = f4 >> 4;                          // Kc/4 = 16 float4 per row
        const int k4 = f4 & 15;
        const float4 v = *(const float4*)&ybase[(size_t)row * Tn + k4 * 4];
        const double m = smean[row];
        float4 c;
        c.x = (float)((double)v.x - m);
        c.y = (float)((double)v.y - m);
        c.z = (float)((double)v.z - m);
        c.w = (float)((double)v.w - m);
        *(float4*)&S[row * PITCH + k4 * 4] = c;
    }
    __syncthreads();

    // compute: thread (ty,tx) -> rows {ty+16a}, cols {tx+16j}
    const int ty = tid >> 4, tx = tid & 15;
    float acc[4][4];
    #pragma unroll
    for (int a = 0; a < 4; ++a)
        #pragma unroll
        for (int j = 0; j < 4; ++j) acc[a][j] = 0.f;

    for (int kq = 0; kq < Kc / 4; ++kq) {
        float4 av[4], bv[4];
        #pragma unroll
        for (int a = 0; a < 4; ++a) av[a] = *(const float4*)&S[(ty + 16 * a) * PITCH + kq * 4];
        #pragma unroll
        for (int j = 0; j < 4; ++j) bv[j] = *(const float4*)&S[(tx + 16 * j) * PITCH + kq * 4];
        #pragma unroll
        for (int a = 0; a < 4; ++a)
            #pragma unroll
            for (int j = 0; j < 4; ++j) {
                acc[a][j] = fmaf(av[a].x, bv[j].x, acc[a][j]);
                acc[a][j] = fmaf(av[a].y, bv[j].y, acc[a][j]);
                acc[a][j] = fmaf(av[a].z, bv[j].z, acc[a][j]);
                acc[a][j] = fmaf(av[a].w, bv[j].w, acc[a][j]);
            }
    }

    float* cb = covf + ((size_t)b << 12);
    #pragma unroll
    for (int a = 0; a < 4; ++a) {
        const int row = ty + 16 * a;
        #pragma unroll
        for (int j = 0; j < 4; ++j)
            atomicAdd(&cb[(row << 6) + tx + 16 * j], acc[a][j]);
    }
}

// ---------------- Kernel C: corr + output (fp64 ratio, NaN-propagating clip) ----------------
// Note: covf is the UNSCALED Gram (no 1/(T-1)) — the scale cancels in corr.
__global__ __launch_bounds__(256) void corr_kernel(
    const float* __restrict__ covf, float* __restrict__ out)
{
    const int i = blockIdx.x * TPB + threadIdx.x;
    if (i >= Bn * Sn * Sn) return;
    const int b = i / (Sn * Sn);
    const int rem = i % (Sn * Sn);
    const int s = rem / Sn, u = rem % Sn;
    const double css = (double)covf[((size_t)b * Sn + s) * Sn + s];
    const double cuu = (double)covf[((size_t)b * Sn + u) * Sn + u];
    const double csu = (double)covf[i];
    double r = csu / sqrt(css * cuu);
    r = (r < -1.0) ? -1.0 : ((r > 1.0) ? 1.0 : r);   // NaN-propagating clip
    out[i] = (float)(1.0 - r);
}

extern "C" void kernel_launch(void* const* d_in, const int* in_sizes, int n_in,
                              void* d_out, int out_size, void* d_ws, size_t ws_size,
                              hipStream_t stream) {
    const float* data = (const float*)d_in[0];
    const float* W1 = (const float*)d_in[1];  const float* b1 = (const float*)d_in[2];
    const float* W2 = (const float*)d_in[3];  const float* b2 = (const float*)d_in[4];
    const float* W3 = (const float*)d_in[5];  const float* b3 = (const float*)d_in[6];
    const float* W4 = (const float*)d_in[7];  const float* b4 = (const float*)d_in[8];
    const float* W5 = (const float*)d_in[9];  const float* b5 = (const float*)d_in[10];
    float* out = (float*)d_out;

    // ws layout: y fp32 (8 MB) | covf fp32 (256 KB) | Rp fp64 (32 KB)
    float* y = (float*)d_ws;
    float* covf = (float*)((char*)d_ws + (size_t)Bn * Sn * Tn * sizeof(float));
    double* Rp = (double*)((char*)covf + (size_t)Bn * Sn * Sn * sizeof(float));

    hipMemsetAsync(covf, 0, (size_t)Bn * Sn * Sn * sizeof(float), stream);
    mlp_kernel<<<Bn * Sn * 4, TPB, 0, stream>>>(data, W1, b1, W2, b2, W3, b3, W4, b4, W5, b5, y, Rp);
    cov_kernel<<<Bn * KS, TPB, 0, stream>>>(y, Rp, covf);
    corr_kernel<<<(Bn * Sn * Sn + TPB - 1) / TPB, TPB, 0, stream>>>(covf, out);
}